// Round 2
// baseline (1593.155 us; speedup 1.0000x reference)
//
#include <hip/hip_runtime.h>
#include <hip/hip_bf16.h>
#include <cstdint>

#define N_NODES 100000
#define N_EDGES 1600000
#define N_GRAPHS 64
#define F_IN 64
#define F_MID 128
#define F_OUT 64

// ---- dtype-agnostic accessors (flags[0]=1 → floats are fp32; flags[1]=1 → ints are int64)
__device__ __forceinline__ float ldF(const void* p, size_t i, int f32) {
    return f32 ? ((const float*)p)[i]
               : __bfloat162float(((const __hip_bfloat16*)p)[i]);
}
__device__ __forceinline__ int ldI(const void* p, size_t i, int i64) {
    return i64 ? (int)((const long long*)p)[i] : ((const int*)p)[i];
}
__device__ __forceinline__ void stF(void* p, size_t i, float v, int f32) {
    if (f32) ((float*)p)[i] = v;
    else     ((__hip_bfloat16*)p)[i] = __float2bfloat16(v);
}

// ---------------- dtype sniffer ----------------------------------------------------
// x: if buffer is fp32, decoding it as bf16 yields wild exponents (random low-mantissa
// halves). if genuinely bf16 (~N(0,1) data / weights), exponents stay near 127.
// edge_index: if int64, odd int32 words (high words of values <1e5) are all zero.
__global__ void GCNEncoder_77214922048129_kernel(const void* x, const void* ei,
                                                 int* flags) {
    __shared__ int cnt_weird, cnt_zero;
    if (threadIdx.x == 0) { cnt_weird = 0; cnt_zero = 0; }
    __syncthreads();
    const unsigned short* u = (const unsigned short*)x;
    int w = 0;
    for (int i = threadIdx.x; i < 2048; i += 256) {
        int e = (u[i] >> 7) & 0xFF;
        if (e == 0xFF || e >= 159 || (e > 0 && e <= 95)) w++;
    }
    atomicAdd(&cnt_weird, w);
    const int* ii = (const int*)ei;
    int z = 0;
    for (int i = threadIdx.x; i < 128; i += 256) {
        if (ii[2 * i + 1] == 0) z++;
    }
    atomicAdd(&cnt_zero, z);
    __syncthreads();
    if (threadIdx.x == 0) {
        flags[0] = (cnt_weird > 64) ? 1 : 0;  // fp32 floats
        flags[1] = (cnt_zero > 64) ? 1 : 0;   // int64 indices
    }
}

// ---------------- degree over col (self-loop added analytically) -------------------
__global__ void k_deg(const void* __restrict__ ei, int* __restrict__ deg,
                      const int* __restrict__ flags) {
    const int i64 = flags[1];
    int e = blockIdx.x * blockDim.x + threadIdx.x;
    if (e < N_EDGES) atomicAdd(&deg[ldI(ei, (size_t)N_EDGES + e, i64)], 1);
}

__global__ void k_dinv(const int* __restrict__ deg, float* __restrict__ dinv) {
    int i = blockIdx.x * blockDim.x + threadIdx.x;
    if (i < N_NODES) dinv[i] = rsqrtf((float)deg[i] + 1.0f);  // +1 = self-loop
}

// ---------------- GEMM1: h1s[n] = (x[n] @ W1) * dinv[n]  (fp32 out) ----------------
#define NPB1 16
__global__ __launch_bounds__(128) void k_gemm1(const void* __restrict__ x,
                                               const void* __restrict__ W1,
                                               const float* __restrict__ dinv,
                                               float* __restrict__ h1s,
                                               const int* __restrict__ flags) {
    const int F32 = flags[0];
    __shared__ float w1s[F_IN * F_MID];
    __shared__ float xs[F_IN];
    for (int i = threadIdx.x; i < F_IN * F_MID; i += 128) w1s[i] = ldF(W1, i, F32);
    const int f = threadIdx.x;
    const int n0 = blockIdx.x * NPB1;
    const int n1 = min(n0 + NPB1, N_NODES);
    for (int n = n0; n < n1; ++n) {
        __syncthreads();  // also covers w1s on first iteration
        if (threadIdx.x < F_IN) xs[threadIdx.x] = ldF(x, (size_t)n * F_IN + threadIdx.x, F32);
        __syncthreads();
        float acc = 0.f;
#pragma unroll
        for (int k = 0; k < F_IN; ++k) acc += xs[k] * w1s[k * F_MID + f];
        h1s[(size_t)n * F_MID + f] = acc * dinv[n];
    }
}

// ---------------- layer-1 edge scatter: agg1[c] += h1s[r] --------------------------
__global__ __launch_bounds__(256) void k_agg1(const void* __restrict__ ei,
                                              const float* __restrict__ h1s,
                                              float* __restrict__ agg1,
                                              const int* __restrict__ flags) {
    const int i64 = flags[1];
    const long long total = (long long)N_EDGES * F_MID;
    const long long stride = (long long)gridDim.x * blockDim.x;
    for (long long idx = (long long)blockIdx.x * blockDim.x + threadIdx.x; idx < total;
         idx += stride) {
        int e = (int)(idx >> 7);
        int f = (int)(idx & 127);
        int r = ldI(ei, e, i64);
        int c = ldI(ei, (size_t)N_EDGES + e, i64);
        atomicAdd(&agg1[(size_t)c * F_MID + f], h1s[(size_t)r * F_MID + f]);
    }
}

// ---------------- fused: finalize1 + LN + ReLU + GEMM2 + dinv scale ----------------
// one wave per node; 4 waves/block
__global__ __launch_bounds__(256) void k_fuse1(
    const float* __restrict__ agg1, const float* __restrict__ h1s,
    const float* __restrict__ dinv, const void* __restrict__ b1,
    const void* __restrict__ lnw, const void* __restrict__ lnb,
    const void* __restrict__ W2, float* __restrict__ a2s,
    const int* __restrict__ flags) {
    const int F32 = flags[0];
    __shared__ float w2s[F_MID * F_OUT];
    __shared__ float b1s[F_MID], lnws[F_MID], lnbs[F_MID];
    __shared__ float us[4][F_MID];
    for (int i = threadIdx.x; i < F_MID * F_OUT; i += 256) w2s[i] = ldF(W2, i, F32);
    if (threadIdx.x < F_MID) {
        b1s[threadIdx.x] = ldF(b1, threadIdx.x, F32);
        lnws[threadIdx.x] = ldF(lnw, threadIdx.x, F32);
        lnbs[threadIdx.x] = ldF(lnb, threadIdx.x, F32);
    }
    __syncthreads();
    const int wid = threadIdx.x >> 6;
    const int lane = threadIdx.x & 63;
    for (int n = blockIdx.x * 4 + wid; n < N_NODES; n += gridDim.x * 4) {
        const float dv = dinv[n];
        const size_t base = (size_t)n * F_MID;
        float t0 = (agg1[base + lane] + h1s[base + lane]) * dv + b1s[lane];
        float t1 = (agg1[base + 64 + lane] + h1s[base + 64 + lane]) * dv + b1s[64 + lane];
        float s = t0 + t1;
#pragma unroll
        for (int off = 32; off > 0; off >>= 1) s += __shfl_down(s, off, 64);
        const float mu = __shfl(s, 0, 64) * (1.f / 128.f);
        float d0 = t0 - mu, d1 = t1 - mu;
        float v = d0 * d0 + d1 * d1;
#pragma unroll
        for (int off = 32; off > 0; off >>= 1) v += __shfl_down(v, off, 64);
        const float rstd = rsqrtf(__shfl(v, 0, 64) * (1.f / 128.f) + 1e-5f);
        float u0 = fmaxf(d0 * rstd * lnws[lane] + lnbs[lane], 0.f);
        float u1 = fmaxf(d1 * rstd * lnws[64 + lane] + lnbs[64 + lane], 0.f);
        us[wid][lane] = u0;
        us[wid][64 + lane] = u1;  // within-wave RAW (lockstep, compiler waits lgkmcnt)
        float acc = 0.f;
#pragma unroll
        for (int k = 0; k < F_MID; ++k) acc += us[wid][k] * w2s[k * F_OUT + lane];
        a2s[(size_t)n * F_OUT + lane] = acc * dv;
    }
}

// ---------------- layer-2 edge scatter: agg2[c] += a2s[r] --------------------------
__global__ __launch_bounds__(256) void k_agg2(const void* __restrict__ ei,
                                              const float* __restrict__ a2s,
                                              float* __restrict__ agg2,
                                              const int* __restrict__ flags) {
    const int i64 = flags[1];
    const long long total = (long long)N_EDGES * F_OUT;
    const long long stride = (long long)gridDim.x * blockDim.x;
    for (long long idx = (long long)blockIdx.x * blockDim.x + threadIdx.x; idx < total;
         idx += stride) {
        int e = (int)(idx >> 6);
        int f = (int)(idx & 63);
        int r = ldI(ei, e, i64);
        int c = ldI(ei, (size_t)N_EDGES + e, i64);
        atomicAdd(&agg2[(size_t)c * F_OUT + f], a2s[(size_t)r * F_OUT + f]);
    }
}

// ---------------- finalize2: h = (agg2 + a2s)*dinv + b2 → out + fp32 keep ----------
__global__ void k_fin2(const float* __restrict__ agg2, float* __restrict__ a2s,
                       const float* __restrict__ dinv, const void* __restrict__ b2,
                       void* __restrict__ out, const int* __restrict__ flags) {
    const int F32 = flags[0];
    int idx = blockIdx.x * blockDim.x + threadIdx.x;
    if (idx < N_NODES * F_OUT) {
        int n = idx >> 6;
        int f = idx & 63;
        float v = (agg2[idx] + a2s[idx]) * dinv[n] + ldF(b2, f, F32);
        a2s[idx] = v;  // fp32 copy for pooling
        stF(out, idx, v, F32);
    }
}

// ---------------- per-graph counts via binary search on sorted batch ---------------
__global__ void k_counts(const void* __restrict__ batch, int* __restrict__ counts,
                         const int* __restrict__ flags) {
    const int i64 = flags[1];
    int g = threadIdx.x;
    if (g < N_GRAPHS) {
        int lo = 0, hi = N_NODES;
        while (lo < hi) { int m = (lo + hi) >> 1; if (ldI(batch, m, i64) < g) lo = m + 1; else hi = m; }
        int lb = lo;
        lo = 0; hi = N_NODES;
        while (lo < hi) { int m = (lo + hi) >> 1; if (ldI(batch, m, i64) <= g) lo = m + 1; else hi = m; }
        counts[g] = lo - lb;
    }
}

// ---------------- pooling: segmented per-wave reduction (batch sorted) -------------
__global__ __launch_bounds__(256) void k_pool(const float* __restrict__ h2,
                                              const void* __restrict__ batch,
                                              float* __restrict__ gsum,
                                              const int* __restrict__ flags) {
    const int i64 = flags[1];
    const int wid = (blockIdx.x * blockDim.x + threadIdx.x) >> 6;
    const int lane = threadIdx.x & 63;
    const int nwaves = (gridDim.x * blockDim.x) >> 6;
    const int per = (N_NODES + nwaves - 1) / nwaves;
    const int start = wid * per;
    const int end = min(start + per, N_NODES);
    if (start >= end) return;
    float acc = 0.f;
    int gcur = ldI(batch, start, i64);
    for (int n = start; n < end; ++n) {
        int g = ldI(batch, n, i64);
        if (g != gcur) {
            atomicAdd(&gsum[gcur * 64 + lane], acc);
            acc = 0.f;
            gcur = g;
        }
        acc += h2[(size_t)n * 64 + lane];
    }
    atomicAdd(&gsum[gcur * 64 + lane], acc);
}

__global__ void k_gout(const float* __restrict__ gsum, const int* __restrict__ counts,
                       void* __restrict__ out, const int* __restrict__ flags) {
    const int F32 = flags[0];
    int idx = blockIdx.x * blockDim.x + threadIdx.x;
    if (idx < N_GRAPHS * 64) {
        int g = idx >> 6;
        float c = (float)max(counts[g], 1);
        stF(out, (size_t)N_NODES * F_OUT + idx, gsum[idx] / c, F32);
    }
}

extern "C" void kernel_launch(void* const* d_in, const int* in_sizes, int n_in,
                              void* d_out, int out_size, void* d_ws, size_t ws_size,
                              hipStream_t stream) {
    const void* x   = d_in[0];
    const void* ei  = d_in[1];
    const void* bat = d_in[2];
    const void* W1  = d_in[3];
    const void* b1  = d_in[4];
    const void* lnw = d_in[5];
    const void* lnb = d_in[6];
    const void* W2  = d_in[7];
    const void* b2  = d_in[8];

    char* ws = (char*)d_ws;
    size_t o = 0;
    auto alloc = [&](size_t bytes) { size_t r = o; o += (bytes + 255) & ~(size_t)255; return r; };
    int*   flags  = (int*)  (ws + alloc(2 * 4));
    float* dinv   = (float*)(ws + alloc((size_t)N_NODES * 4));
    int*   deg    = (int*)  (ws + alloc((size_t)N_NODES * 4));
    float* h1s    = (float*)(ws + alloc((size_t)N_NODES * F_MID * 4));  // reused as agg2
    float* agg1   = (float*)(ws + alloc((size_t)N_NODES * F_MID * 4));
    float* a2s    = (float*)(ws + alloc((size_t)N_NODES * F_OUT * 4));
    float* gsum   = (float*)(ws + alloc((size_t)N_GRAPHS * 64 * 4));
    int*   counts = (int*)  (ws + alloc((size_t)N_GRAPHS * 4));
    float* agg2 = h1s;  // h1s dead after k_fuse1

    hipMemsetAsync(deg, 0, (size_t)N_NODES * 4, stream);
    hipMemsetAsync(agg1, 0, (size_t)N_NODES * F_MID * 4, stream);
    hipMemsetAsync(gsum, 0, (size_t)N_GRAPHS * 64 * 4, stream);

    GCNEncoder_77214922048129_kernel<<<1, 256, 0, stream>>>(x, ei, flags);
    k_deg<<<(N_EDGES + 255) / 256, 256, 0, stream>>>(ei, deg, flags);
    k_dinv<<<(N_NODES + 255) / 256, 256, 0, stream>>>(deg, dinv);
    k_gemm1<<<(N_NODES + NPB1 - 1) / NPB1, 128, 0, stream>>>(x, W1, dinv, h1s, flags);
    k_agg1<<<8192, 256, 0, stream>>>(ei, h1s, agg1, flags);
    k_fuse1<<<1024, 256, 0, stream>>>(agg1, h1s, dinv, b1, lnw, lnb, W2, a2s, flags);
    hipMemsetAsync(agg2, 0, (size_t)N_NODES * F_OUT * 4, stream);
    k_agg2<<<8192, 256, 0, stream>>>(ei, a2s, agg2, flags);
    k_fin2<<<(N_NODES * F_OUT + 255) / 256, 256, 0, stream>>>(agg2, a2s, dinv, b2, d_out, flags);
    k_counts<<<1, 64, 0, stream>>>(bat, counts, flags);
    k_pool<<<512, 256, 0, stream>>>(a2s, bat, gsum, flags);
    k_gout<<<(N_GRAPHS * 64 + 255) / 256, 256, 0, stream>>>(gsum, counts, d_out, flags);
}

// Round 3
// 1141.662 us; speedup vs baseline: 1.3955x; 1.3955x over previous
//
#include <hip/hip_runtime.h>
#include <hip/hip_bf16.h>
#include <cstdint>

#define N_NODES 100000
#define N_EDGES 1600000
#define N_GRAPHS 64
#define F_IN 64
#define F_MID 128
#define F_OUT 64

// ---- dtype-agnostic accessors (flags[0]=1 → floats are fp32; flags[1]=1 → ints are int64)
__device__ __forceinline__ float ldF(const void* p, size_t i, int f32) {
    return f32 ? ((const float*)p)[i]
               : __bfloat162float(((const __hip_bfloat16*)p)[i]);
}
__device__ __forceinline__ int ldI(const void* p, size_t i, int i64) {
    return i64 ? (int)((const long long*)p)[i] : ((const int*)p)[i];
}
__device__ __forceinline__ void stF(void* p, size_t i, float v, int f32) {
    if (f32) ((float*)p)[i] = v;
    else     ((__hip_bfloat16*)p)[i] = __float2bfloat16(v);
}

// ---------------- dtype sniffer ----------------------------------------------------
__global__ void GCNEncoder_77214922048129_kernel(const void* x, const void* ei,
                                                 int* flags) {
    __shared__ int cnt_weird, cnt_zero;
    if (threadIdx.x == 0) { cnt_weird = 0; cnt_zero = 0; }
    __syncthreads();
    const unsigned short* u = (const unsigned short*)x;
    int w = 0;
    for (int i = threadIdx.x; i < 2048; i += 256) {
        int e = (u[i] >> 7) & 0xFF;
        if (e == 0xFF || e >= 159 || (e > 0 && e <= 95)) w++;
    }
    atomicAdd(&cnt_weird, w);
    const int* ii = (const int*)ei;
    int z = 0;
    for (int i = threadIdx.x; i < 128; i += 256) {
        if (ii[2 * i + 1] == 0) z++;
    }
    atomicAdd(&cnt_zero, z);
    __syncthreads();
    if (threadIdx.x == 0) {
        flags[0] = (cnt_weird > 64) ? 1 : 0;  // fp32 floats
        flags[1] = (cnt_zero > 64) ? 1 : 0;   // int64 indices
    }
}

// ---------------- degree over col (self-loop added analytically) -------------------
__global__ void k_deg(const void* __restrict__ ei, int* __restrict__ deg,
                      const int* __restrict__ flags) {
    const int i64 = flags[1];
    int e = blockIdx.x * blockDim.x + threadIdx.x;
    if (e < N_EDGES) atomicAdd(&deg[ldI(ei, (size_t)N_EDGES + e, i64)], 1);
}

__global__ void k_dinv(const int* __restrict__ deg, float* __restrict__ dinv) {
    int i = blockIdx.x * blockDim.x + threadIdx.x;
    if (i < N_NODES) dinv[i] = rsqrtf((float)deg[i] + 1.0f);  // +1 = self-loop
}

// ---------------- CSR build: exclusive scan of deg (single block) ------------------
#define SCAN_T 1024
#define SEG 98  // ceil(100000/1024)
__global__ __launch_bounds__(SCAN_T) void k_scan(const int* __restrict__ deg,
                                                 int* __restrict__ rowptr,
                                                 int* __restrict__ cursor) {
    __shared__ int part[SCAN_T];
    const int t = threadIdx.x;
    const int s0 = t * SEG, s1 = min(s0 + SEG, N_NODES);
    int sum = 0;
    for (int i = s0; i < s1; ++i) sum += deg[i];
    part[t] = sum;
    __syncthreads();
    for (int off = 1; off < SCAN_T; off <<= 1) {
        int v = (t >= off) ? part[t - off] : 0;
        __syncthreads();
        part[t] += v;
        __syncthreads();
    }
    int run = (t == 0) ? 0 : part[t - 1];
    for (int i = s0; i < s1; ++i) {
        rowptr[i] = run;
        cursor[i] = run;
        run += deg[i];
    }
    if (t == SCAN_T - 1) rowptr[N_NODES] = N_EDGES;
}

// ---------------- CSR scatter: src[pos(c)] = r -------------------------------------
__global__ __launch_bounds__(256) void k_csr(const void* __restrict__ ei,
                                             int* __restrict__ cursor,
                                             int* __restrict__ src,
                                             const int* __restrict__ flags) {
    const int i64 = flags[1];
    int e = blockIdx.x * blockDim.x + threadIdx.x;
    if (e < N_EDGES) {
        int r = ldI(ei, e, i64);
        int c = ldI(ei, (size_t)N_EDGES + e, i64);
        int pos = atomicAdd(&cursor[c], 1);
        src[pos] = r;
    }
}

// ---------------- GEMM1: h1s[n] = (x[n] @ W1) * dinv[n]  (fp32 out) ----------------
#define NPB1 64
__global__ __launch_bounds__(128) void k_gemm1(const void* __restrict__ x,
                                               const void* __restrict__ W1,
                                               const float* __restrict__ dinv,
                                               float* __restrict__ h1s,
                                               const int* __restrict__ flags) {
    const int F32 = flags[0];
    __shared__ float w1s[F_IN * F_MID];
    __shared__ float xs[F_IN];
    for (int i = threadIdx.x; i < F_IN * F_MID; i += 128) w1s[i] = ldF(W1, i, F32);
    const int f = threadIdx.x;
    const int n0 = blockIdx.x * NPB1;
    const int n1 = min(n0 + NPB1, N_NODES);
    for (int n = n0; n < n1; ++n) {
        __syncthreads();  // also covers w1s on first iteration
        if (threadIdx.x < F_IN) xs[threadIdx.x] = ldF(x, (size_t)n * F_IN + threadIdx.x, F32);
        __syncthreads();
        float acc = 0.f;
#pragma unroll
        for (int k = 0; k < F_IN; ++k) acc += xs[k] * w1s[k * F_MID + f];
        h1s[(size_t)n * F_MID + f] = acc * dinv[n];
    }
}

// ------ fused layer1: CSR gather-sum + self + dinv + b1 + LN + ReLU + GEMM2 --------
// one wave per node (grid-stride); 4 waves/block
__global__ __launch_bounds__(256) void k_gather1(
    const int* __restrict__ rowptr, const int* __restrict__ src,
    const float* __restrict__ h1s, const float* __restrict__ dinv,
    const void* __restrict__ b1, const void* __restrict__ lnw,
    const void* __restrict__ lnb, const void* __restrict__ W2,
    float* __restrict__ a2s, const int* __restrict__ flags) {
    const int F32 = flags[0];
    __shared__ float w2s[F_MID * F_OUT];
    __shared__ float b1s[F_MID], lnws[F_MID], lnbs[F_MID];
    __shared__ float us[4][F_MID];
    for (int i = threadIdx.x; i < F_MID * F_OUT; i += 256) w2s[i] = ldF(W2, i, F32);
    if (threadIdx.x < F_MID) {
        b1s[threadIdx.x] = ldF(b1, threadIdx.x, F32);
        lnws[threadIdx.x] = ldF(lnw, threadIdx.x, F32);
        lnbs[threadIdx.x] = ldF(lnb, threadIdx.x, F32);
    }
    __syncthreads();
    const int wid = threadIdx.x >> 6;
    const int lane = threadIdx.x & 63;
    for (int n = blockIdx.x * 4 + wid; n < N_NODES; n += gridDim.x * 4) {
        const int beg = rowptr[n], end = rowptr[n + 1];
        float acc0 = 0.f, acc1 = 0.f;
        for (int base = beg; base < end; base += 64) {
            const int cnt = min(64, end - base);
            int myidx = (lane < cnt) ? src[base + lane] : 0;
            for (int j = 0; j < cnt; ++j) {
                const size_t rb = (size_t)__shfl(myidx, j, 64) * F_MID;
                acc0 += h1s[rb + lane];
                acc1 += h1s[rb + 64 + lane];
            }
        }
        const float dv = dinv[n];
        const size_t nb = (size_t)n * F_MID;
        float t0 = (acc0 + h1s[nb + lane]) * dv + b1s[lane];
        float t1 = (acc1 + h1s[nb + 64 + lane]) * dv + b1s[64 + lane];
        float s = t0 + t1;
#pragma unroll
        for (int off = 32; off > 0; off >>= 1) s += __shfl_down(s, off, 64);
        const float mu = __shfl(s, 0, 64) * (1.f / 128.f);
        float d0 = t0 - mu, d1 = t1 - mu;
        float v = d0 * d0 + d1 * d1;
#pragma unroll
        for (int off = 32; off > 0; off >>= 1) v += __shfl_down(v, off, 64);
        const float rstd = rsqrtf(__shfl(v, 0, 64) * (1.f / 128.f) + 1e-5f);
        float u0 = fmaxf(d0 * rstd * lnws[lane] + lnbs[lane], 0.f);
        float u1 = fmaxf(d1 * rstd * lnws[64 + lane] + lnbs[64 + lane], 0.f);
        us[wid][lane] = u0;
        us[wid][64 + lane] = u1;  // within-wave RAW (lockstep, compiler waits lgkmcnt)
        float acc = 0.f;
#pragma unroll
        for (int k = 0; k < F_MID; ++k) acc += us[wid][k] * w2s[k * F_OUT + lane];
        a2s[(size_t)n * F_OUT + lane] = acc * dv;
    }
}

// ------ fused layer2: CSR gather-sum + self + dinv + b2 → out (+fp32 keep) ---------
__global__ __launch_bounds__(256) void k_gather2(
    const int* __restrict__ rowptr, const int* __restrict__ src,
    const float* __restrict__ a2s, const float* __restrict__ dinv,
    const void* __restrict__ b2, void* __restrict__ out,
    float* __restrict__ h2f, const int* __restrict__ flags) {
    const int F32 = flags[0];
    __shared__ float b2s[F_OUT];
    if (threadIdx.x < F_OUT) b2s[threadIdx.x] = ldF(b2, threadIdx.x, F32);
    __syncthreads();
    const int wid = threadIdx.x >> 6;
    const int lane = threadIdx.x & 63;
    for (int n = blockIdx.x * 4 + wid; n < N_NODES; n += gridDim.x * 4) {
        const int beg = rowptr[n], end = rowptr[n + 1];
        float acc = 0.f;
        for (int base = beg; base < end; base += 64) {
            const int cnt = min(64, end - base);
            int myidx = (lane < cnt) ? src[base + lane] : 0;
            for (int j = 0; j < cnt; ++j) {
                acc += a2s[(size_t)__shfl(myidx, j, 64) * F_OUT + lane];
            }
        }
        const size_t idx = (size_t)n * F_OUT + lane;
        float v = (acc + a2s[idx]) * dinv[n] + b2s[lane];
        h2f[idx] = v;
        stF(out, idx, v, F32);
    }
}

// ---------------- per-graph counts via binary search on sorted batch ---------------
__global__ void k_counts(const void* __restrict__ batch, int* __restrict__ counts,
                         const int* __restrict__ flags) {
    const int i64 = flags[1];
    int g = threadIdx.x;
    if (g < N_GRAPHS) {
        int lo = 0, hi = N_NODES;
        while (lo < hi) { int m = (lo + hi) >> 1; if (ldI(batch, m, i64) < g) lo = m + 1; else hi = m; }
        int lb = lo;
        lo = 0; hi = N_NODES;
        while (lo < hi) { int m = (lo + hi) >> 1; if (ldI(batch, m, i64) <= g) lo = m + 1; else hi = m; }
        counts[g] = lo - lb;
    }
}

// ---------------- pooling: segmented per-wave reduction (batch sorted) -------------
__global__ __launch_bounds__(256) void k_pool(const float* __restrict__ h2,
                                              const void* __restrict__ batch,
                                              float* __restrict__ gsum,
                                              const int* __restrict__ flags) {
    const int i64 = flags[1];
    const int wid = (blockIdx.x * blockDim.x + threadIdx.x) >> 6;
    const int lane = threadIdx.x & 63;
    const int nwaves = (gridDim.x * blockDim.x) >> 6;
    const int per = (N_NODES + nwaves - 1) / nwaves;
    const int start = wid * per;
    const int end = min(start + per, N_NODES);
    if (start >= end) return;
    float acc = 0.f;
    int gcur = ldI(batch, start, i64);
    for (int n = start; n < end; ++n) {
        int g = ldI(batch, n, i64);
        if (g != gcur) {
            atomicAdd(&gsum[gcur * 64 + lane], acc);
            acc = 0.f;
            gcur = g;
        }
        acc += h2[(size_t)n * 64 + lane];
    }
    atomicAdd(&gsum[gcur * 64 + lane], acc);
}

__global__ void k_gout(const float* __restrict__ gsum, const int* __restrict__ counts,
                       void* __restrict__ out, const int* __restrict__ flags) {
    const int F32 = flags[0];
    int idx = blockIdx.x * blockDim.x + threadIdx.x;
    if (idx < N_GRAPHS * 64) {
        int g = idx >> 6;
        float c = (float)max(counts[g], 1);
        stF(out, (size_t)N_NODES * F_OUT + idx, gsum[idx] / c, F32);
    }
}

extern "C" void kernel_launch(void* const* d_in, const int* in_sizes, int n_in,
                              void* d_out, int out_size, void* d_ws, size_t ws_size,
                              hipStream_t stream) {
    const void* x   = d_in[0];
    const void* ei  = d_in[1];
    const void* bat = d_in[2];
    const void* W1  = d_in[3];
    const void* b1  = d_in[4];
    const void* lnw = d_in[5];
    const void* lnb = d_in[6];
    const void* W2  = d_in[7];
    const void* b2  = d_in[8];

    char* ws = (char*)d_ws;
    size_t o = 0;
    auto alloc = [&](size_t bytes) { size_t r = o; o += (bytes + 255) & ~(size_t)255; return r; };
    int*   flags  = (int*)  (ws + alloc(2 * 4));
    float* dinv   = (float*)(ws + alloc((size_t)N_NODES * 4));
    int*   deg    = (int*)  (ws + alloc((size_t)N_NODES * 4));
    int*   rowptr = (int*)  (ws + alloc((size_t)(N_NODES + 1) * 4));
    int*   cursor = (int*)  (ws + alloc((size_t)N_NODES * 4));
    int*   srcidx = (int*)  (ws + alloc((size_t)N_EDGES * 4));
    float* h1s    = (float*)(ws + alloc((size_t)N_NODES * F_MID * 4));
    float* a2s    = (float*)(ws + alloc((size_t)N_NODES * F_OUT * 4));
    float* h2f    = (float*)(ws + alloc((size_t)N_NODES * F_OUT * 4));
    float* gsum   = (float*)(ws + alloc((size_t)N_GRAPHS * 64 * 4));
    int*   counts = (int*)  (ws + alloc((size_t)N_GRAPHS * 4));

    hipMemsetAsync(deg, 0, (size_t)N_NODES * 4, stream);
    hipMemsetAsync(gsum, 0, (size_t)N_GRAPHS * 64 * 4, stream);

    GCNEncoder_77214922048129_kernel<<<1, 256, 0, stream>>>(x, ei, flags);
    k_deg<<<(N_EDGES + 255) / 256, 256, 0, stream>>>(ei, deg, flags);
    k_dinv<<<(N_NODES + 255) / 256, 256, 0, stream>>>(deg, dinv);
    k_scan<<<1, SCAN_T, 0, stream>>>(deg, rowptr, cursor);
    k_csr<<<(N_EDGES + 255) / 256, 256, 0, stream>>>(ei, cursor, srcidx, flags);
    k_gemm1<<<(N_NODES + NPB1 - 1) / NPB1, 128, 0, stream>>>(x, W1, dinv, h1s, flags);
    k_gather1<<<2048, 256, 0, stream>>>(rowptr, srcidx, h1s, dinv, b1, lnw, lnb, W2, a2s, flags);
    k_gather2<<<2048, 256, 0, stream>>>(rowptr, srcidx, a2s, dinv, b2, d_out, h2f, flags);
    k_counts<<<1, 64, 0, stream>>>(bat, counts, flags);
    k_pool<<<512, 256, 0, stream>>>(h2f, bat, gsum, flags);
    k_gout<<<(N_GRAPHS * 64 + 255) / 256, 256, 0, stream>>>(gsum, counts, d_out, flags);
}

// Round 4
// 987.869 us; speedup vs baseline: 1.6127x; 1.1557x over previous
//
#include <hip/hip_runtime.h>
#include <hip/hip_bf16.h>
#include <cstdint>

#define N_NODES 100000
#define N_EDGES 1600000
#define N_GRAPHS 64
#define F_IN 64
#define F_MID 128
#define F_OUT 64

// ---- dtype-agnostic accessors (flags[0]=1 → floats are fp32; flags[1]=1 → ints are int64)
__device__ __forceinline__ float ldF(const void* p, size_t i, int f32) {
    return f32 ? ((const float*)p)[i]
               : __bfloat162float(((const __hip_bfloat16*)p)[i]);
}
__device__ __forceinline__ int ldI(const void* p, size_t i, int i64) {
    return i64 ? (int)((const long long*)p)[i] : ((const int*)p)[i];
}
__device__ __forceinline__ void stF(void* p, size_t i, float v, int f32) {
    if (f32) ((float*)p)[i] = v;
    else     ((__hip_bfloat16*)p)[i] = __float2bfloat16(v);
}

// ---------------- dtype sniffer ----------------------------------------------------
__global__ void GCNEncoder_77214922048129_kernel(const void* x, const void* ei,
                                                 int* flags) {
    __shared__ int cnt_weird, cnt_zero;
    if (threadIdx.x == 0) { cnt_weird = 0; cnt_zero = 0; }
    __syncthreads();
    const unsigned short* u = (const unsigned short*)x;
    int w = 0;
    for (int i = threadIdx.x; i < 2048; i += 256) {
        int e = (u[i] >> 7) & 0xFF;
        if (e == 0xFF || e >= 159 || (e > 0 && e <= 95)) w++;
    }
    atomicAdd(&cnt_weird, w);
    const int* ii = (const int*)ei;
    int z = 0;
    for (int i = threadIdx.x; i < 128; i += 256) {
        if (ii[2 * i + 1] == 0) z++;
    }
    atomicAdd(&cnt_zero, z);
    __syncthreads();
    if (threadIdx.x == 0) {
        flags[0] = (cnt_weird > 64) ? 1 : 0;  // fp32 floats
        flags[1] = (cnt_zero > 64) ? 1 : 0;   // int64 indices
    }
}

// ---------------- degree over col (self-loop added analytically) -------------------
__global__ void k_deg(const void* __restrict__ ei, int* __restrict__ deg,
                      const int* __restrict__ flags) {
    const int i64 = flags[1];
    int e = blockIdx.x * blockDim.x + threadIdx.x;
    if (e < N_EDGES) atomicAdd(&deg[ldI(ei, (size_t)N_EDGES + e, i64)], 1);
}

__global__ void k_dinv(const int* __restrict__ deg, float* __restrict__ dinv) {
    int i = blockIdx.x * blockDim.x + threadIdx.x;
    if (i < N_NODES) dinv[i] = rsqrtf((float)deg[i] + 1.0f);  // +1 = self-loop
}

// ---------------- CSR build: exclusive scan of deg (single block) ------------------
#define SCAN_T 1024
#define SEG 98  // ceil(100000/1024)
__global__ __launch_bounds__(SCAN_T) void k_scan(const int* __restrict__ deg,
                                                 int* __restrict__ rowptr,
                                                 int* __restrict__ cursor) {
    __shared__ int part[SCAN_T];
    const int t = threadIdx.x;
    const int s0 = t * SEG, s1 = min(s0 + SEG, N_NODES);
    int sum = 0;
    for (int i = s0; i < s1; ++i) sum += deg[i];
    part[t] = sum;
    __syncthreads();
    for (int off = 1; off < SCAN_T; off <<= 1) {
        int v = (t >= off) ? part[t - off] : 0;
        __syncthreads();
        part[t] += v;
        __syncthreads();
    }
    int run = (t == 0) ? 0 : part[t - 1];
    for (int i = s0; i < s1; ++i) {
        rowptr[i] = run;
        cursor[i] = run;
        run += deg[i];
    }
    if (t == SCAN_T - 1) rowptr[N_NODES] = N_EDGES;
}

// ---------------- CSR scatter: src[pos(c)] = r -------------------------------------
__global__ __launch_bounds__(256) void k_csr(const void* __restrict__ ei,
                                             int* __restrict__ cursor,
                                             int* __restrict__ src,
                                             const int* __restrict__ flags) {
    const int i64 = flags[1];
    int e = blockIdx.x * blockDim.x + threadIdx.x;
    if (e < N_EDGES) {
        int r = ldI(ei, e, i64);
        int c = ldI(ei, (size_t)N_EDGES + e, i64);
        int pos = atomicAdd(&cursor[c], 1);
        src[pos] = r;
    }
}

// ---------------- GEMM1: h1s[n] = (x[n] @ W1) * dinv[n]  (fp32 out) ----------------
#define NPB1 64
__global__ __launch_bounds__(128) void k_gemm1(const void* __restrict__ x,
                                               const void* __restrict__ W1,
                                               const float* __restrict__ dinv,
                                               float* __restrict__ h1s,
                                               const int* __restrict__ flags) {
    const int F32 = flags[0];
    __shared__ float w1s[F_IN * F_MID];
    __shared__ float xs[F_IN];
    for (int i = threadIdx.x; i < F_IN * F_MID; i += 128) w1s[i] = ldF(W1, i, F32);
    const int f = threadIdx.x;
    const int n0 = blockIdx.x * NPB1;
    const int n1 = min(n0 + NPB1, N_NODES);
    for (int n = n0; n < n1; ++n) {
        __syncthreads();  // also covers w1s on first iteration
        if (threadIdx.x < F_IN) xs[threadIdx.x] = ldF(x, (size_t)n * F_IN + threadIdx.x, F32);
        __syncthreads();
        float acc = 0.f;
#pragma unroll
        for (int k = 0; k < F_IN; ++k) acc += xs[k] * w1s[k * F_MID + f];
        h1s[(size_t)n * F_MID + f] = acc * dinv[n];
    }
}

// ------ fused layer1: CSR gather-sum + self + dinv + b1 + LN + ReLU + GEMM2 --------
// one wave per node (grid-stride); 8 waves/block; scalar CSR loads + 4-deep MLP
#define G1W 8
__global__ __launch_bounds__(64 * G1W) void k_gather1(
    const int* __restrict__ rowptr, const int* __restrict__ src,
    const float* __restrict__ h1s, const float* __restrict__ dinv,
    const void* __restrict__ b1, const void* __restrict__ lnw,
    const void* __restrict__ lnb, const void* __restrict__ W2,
    float* __restrict__ a2s, const int* __restrict__ flags) {
    const int F32 = flags[0];
    __shared__ float w2s[F_MID * F_OUT];
    __shared__ float b1s[F_MID], lnws[F_MID], lnbs[F_MID];
    __shared__ float us[G1W][F_MID];
    for (int i = threadIdx.x; i < F_MID * F_OUT; i += 64 * G1W) w2s[i] = ldF(W2, i, F32);
    if (threadIdx.x < F_MID) {
        b1s[threadIdx.x] = ldF(b1, threadIdx.x, F32);
        lnws[threadIdx.x] = ldF(lnw, threadIdx.x, F32);
        lnbs[threadIdx.x] = ldF(lnb, threadIdx.x, F32);
    }
    __syncthreads();
    const int wid = threadIdx.x >> 6;
    const int lane = threadIdx.x & 63;
    const float2* __restrict__ h1v = (const float2*)h1s;  // row = 64 float2
    for (int n0 = blockIdx.x * G1W + wid; n0 < N_NODES; n0 += gridDim.x * G1W) {
        const int n = __builtin_amdgcn_readfirstlane(n0);  // force SGPR → scalar CSR loads
        const int beg = rowptr[n], end = rowptr[n + 1];
        float ax0 = 0.f, ay0 = 0.f, ax1 = 0.f, ay1 = 0.f;
        int jj = beg;
        for (; jj + 4 <= end; jj += 4) {
            const int r0 = src[jj], r1 = src[jj + 1], r2 = src[jj + 2], r3 = src[jj + 3];
            const float2 v0 = h1v[(size_t)r0 * 64 + lane];
            const float2 v1 = h1v[(size_t)r1 * 64 + lane];
            const float2 v2 = h1v[(size_t)r2 * 64 + lane];
            const float2 v3 = h1v[(size_t)r3 * 64 + lane];
            ax0 += v0.x + v1.x; ay0 += v0.y + v1.y;
            ax1 += v2.x + v3.x; ay1 += v2.y + v3.y;
        }
        for (; jj < end; ++jj) {
            const float2 v = h1v[(size_t)src[jj] * 64 + lane];
            ax0 += v.x; ay0 += v.y;
        }
        const float2 sv = h1v[(size_t)n * 64 + lane];
        const float dv = dinv[n];
        const float2 b1v = ((const float2*)b1s)[lane];
        float t0 = (ax0 + ax1 + sv.x) * dv + b1v.x;
        float t1 = (ay0 + ay1 + sv.y) * dv + b1v.y;
        float s = t0 + t1;
#pragma unroll
        for (int off = 32; off > 0; off >>= 1) s += __shfl_down(s, off, 64);
        const float mu = __shfl(s, 0, 64) * (1.f / 128.f);
        float d0 = t0 - mu, d1 = t1 - mu;
        float v = d0 * d0 + d1 * d1;
#pragma unroll
        for (int off = 32; off > 0; off >>= 1) v += __shfl_down(v, off, 64);
        const float rstd = rsqrtf(__shfl(v, 0, 64) * (1.f / 128.f) + 1e-5f);
        const float2 lwv = ((const float2*)lnws)[lane];
        const float2 lbv = ((const float2*)lnbs)[lane];
        float2 uv;
        uv.x = fmaxf(d0 * rstd * lwv.x + lbv.x, 0.f);
        uv.y = fmaxf(d1 * rstd * lwv.y + lbv.y, 0.f);
        ((float2*)&us[wid][0])[lane] = uv;  // within-wave RAW (lockstep, lgkmcnt wait)
        float acc = 0.f;
#pragma unroll
        for (int k = 0; k < F_MID; ++k) acc += us[wid][k] * w2s[k * F_OUT + lane];
        a2s[(size_t)n * F_OUT + lane] = acc * dv;
    }
}

// ------ fused layer2: CSR gather-sum + self + dinv + b2 → out (+fp32 keep) ---------
__global__ __launch_bounds__(256) void k_gather2(
    const int* __restrict__ rowptr, const int* __restrict__ src,
    const float* __restrict__ a2s, const float* __restrict__ dinv,
    const void* __restrict__ b2, void* __restrict__ out,
    float* __restrict__ h2f, const int* __restrict__ flags) {
    const int F32 = flags[0];
    __shared__ float b2s[F_OUT];
    if (threadIdx.x < F_OUT) b2s[threadIdx.x] = ldF(b2, threadIdx.x, F32);
    __syncthreads();
    const int wid = threadIdx.x >> 6;
    const int lane = threadIdx.x & 63;
    for (int n0 = blockIdx.x * 4 + wid; n0 < N_NODES; n0 += gridDim.x * 4) {
        const int n = __builtin_amdgcn_readfirstlane(n0);
        const int beg = rowptr[n], end = rowptr[n + 1];
        float a0 = 0.f, a1 = 0.f;
        int jj = beg;
        for (; jj + 8 <= end; jj += 8) {
            const float v0 = a2s[(size_t)src[jj + 0] * F_OUT + lane];
            const float v1 = a2s[(size_t)src[jj + 1] * F_OUT + lane];
            const float v2 = a2s[(size_t)src[jj + 2] * F_OUT + lane];
            const float v3 = a2s[(size_t)src[jj + 3] * F_OUT + lane];
            const float v4 = a2s[(size_t)src[jj + 4] * F_OUT + lane];
            const float v5 = a2s[(size_t)src[jj + 5] * F_OUT + lane];
            const float v6 = a2s[(size_t)src[jj + 6] * F_OUT + lane];
            const float v7 = a2s[(size_t)src[jj + 7] * F_OUT + lane];
            a0 += (v0 + v1) + (v2 + v3);
            a1 += (v4 + v5) + (v6 + v7);
        }
        for (; jj < end; ++jj) a0 += a2s[(size_t)src[jj] * F_OUT + lane];
        const size_t idx = (size_t)n * F_OUT + lane;
        float v = (a0 + a1 + a2s[idx]) * dinv[n] + b2s[lane];
        h2f[idx] = v;
        stF(out, idx, v, F32);
    }
}

// ---------------- per-graph counts via binary search on sorted batch ---------------
__global__ void k_counts(const void* __restrict__ batch, int* __restrict__ counts,
                         const int* __restrict__ flags) {
    const int i64 = flags[1];
    int g = threadIdx.x;
    if (g < N_GRAPHS) {
        int lo = 0, hi = N_NODES;
        while (lo < hi) { int m = (lo + hi) >> 1; if (ldI(batch, m, i64) < g) lo = m + 1; else hi = m; }
        int lb = lo;
        lo = 0; hi = N_NODES;
        while (lo < hi) { int m = (lo + hi) >> 1; if (ldI(batch, m, i64) <= g) lo = m + 1; else hi = m; }
        counts[g] = lo - lb;
    }
}

// ---------------- pooling: segmented per-wave reduction (batch sorted) -------------
__global__ __launch_bounds__(256) void k_pool(const float* __restrict__ h2,
                                              const void* __restrict__ batch,
                                              float* __restrict__ gsum,
                                              const int* __restrict__ flags) {
    const int i64 = flags[1];
    const int wid = (blockIdx.x * blockDim.x + threadIdx.x) >> 6;
    const int lane = threadIdx.x & 63;
    const int nwaves = (gridDim.x * blockDim.x) >> 6;
    const int per = (N_NODES + nwaves - 1) / nwaves;
    const int start = wid * per;
    const int end = min(start + per, N_NODES);
    if (start >= end) return;
    float acc = 0.f;
    int gcur = ldI(batch, start, i64);
    for (int n = start; n < end; ++n) {
        int g = ldI(batch, n, i64);
        if (g != gcur) {
            atomicAdd(&gsum[gcur * 64 + lane], acc);
            acc = 0.f;
            gcur = g;
        }
        acc += h2[(size_t)n * 64 + lane];
    }
    atomicAdd(&gsum[gcur * 64 + lane], acc);
}

__global__ void k_gout(const float* __restrict__ gsum, const int* __restrict__ counts,
                       void* __restrict__ out, const int* __restrict__ flags) {
    const int F32 = flags[0];
    int idx = blockIdx.x * blockDim.x + threadIdx.x;
    if (idx < N_GRAPHS * 64) {
        int g = idx >> 6;
        float c = (float)max(counts[g], 1);
        stF(out, (size_t)N_NODES * F_OUT + idx, gsum[idx] / c, F32);
    }
}

extern "C" void kernel_launch(void* const* d_in, const int* in_sizes, int n_in,
                              void* d_out, int out_size, void* d_ws, size_t ws_size,
                              hipStream_t stream) {
    const void* x   = d_in[0];
    const void* ei  = d_in[1];
    const void* bat = d_in[2];
    const void* W1  = d_in[3];
    const void* b1  = d_in[4];
    const void* lnw = d_in[5];
    const void* lnb = d_in[6];
    const void* W2  = d_in[7];
    const void* b2  = d_in[8];

    char* ws = (char*)d_ws;
    size_t o = 0;
    auto alloc = [&](size_t bytes) { size_t r = o; o += (bytes + 255) & ~(size_t)255; return r; };
    int*   flags  = (int*)  (ws + alloc(2 * 4));
    float* dinv   = (float*)(ws + alloc((size_t)N_NODES * 4));
    int*   deg    = (int*)  (ws + alloc((size_t)N_NODES * 4));
    int*   rowptr = (int*)  (ws + alloc((size_t)(N_NODES + 1) * 4));
    int*   cursor = (int*)  (ws + alloc((size_t)N_NODES * 4));
    int*   srcidx = (int*)  (ws + alloc((size_t)N_EDGES * 4));
    float* h1s    = (float*)(ws + alloc((size_t)N_NODES * F_MID * 4));
    float* a2s    = (float*)(ws + alloc((size_t)N_NODES * F_OUT * 4));
    float* h2f    = (float*)(ws + alloc((size_t)N_NODES * F_OUT * 4));
    float* gsum   = (float*)(ws + alloc((size_t)N_GRAPHS * 64 * 4));
    int*   counts = (int*)  (ws + alloc((size_t)N_GRAPHS * 4));

    hipMemsetAsync(deg, 0, (size_t)N_NODES * 4, stream);
    hipMemsetAsync(gsum, 0, (size_t)N_GRAPHS * 64 * 4, stream);

    GCNEncoder_77214922048129_kernel<<<1, 256, 0, stream>>>(x, ei, flags);
    k_deg<<<(N_EDGES + 255) / 256, 256, 0, stream>>>(ei, deg, flags);
    k_dinv<<<(N_NODES + 255) / 256, 256, 0, stream>>>(deg, dinv);
    k_scan<<<1, SCAN_T, 0, stream>>>(deg, rowptr, cursor);
    k_csr<<<(N_EDGES + 255) / 256, 256, 0, stream>>>(ei, cursor, srcidx, flags);
    k_gemm1<<<(N_NODES + NPB1 - 1) / NPB1, 128, 0, stream>>>(x, W1, dinv, h1s, flags);
    k_gather1<<<1024, 64 * G1W, 0, stream>>>(rowptr, srcidx, h1s, dinv, b1, lnw, lnb, W2,
                                             a2s, flags);
    k_gather2<<<4096, 256, 0, stream>>>(rowptr, srcidx, a2s, dinv, b2, d_out, h2f, flags);
    k_counts<<<1, 64, 0, stream>>>(bat, counts, flags);
    k_pool<<<512, 256, 0, stream>>>(h2f, bat, gsum, flags);
    k_gout<<<(N_GRAPHS * 64 + 255) / 256, 256, 0, stream>>>(gsum, counts, d_out, flags);
}

// Round 5
// 767.831 us; speedup vs baseline: 2.0749x; 1.2866x over previous
//
#include <hip/hip_runtime.h>
#include <hip/hip_bf16.h>
#include <cstdint>

#define N_NODES 100000
#define N_EDGES 1600000
#define N_GRAPHS 64
#define F_IN 64
#define F_MID 128
#define F_OUT 64

// ---- dtype-agnostic accessors (flags[0]=1 → floats are fp32; flags[1]=1 → ints are int64)
__device__ __forceinline__ float ldF(const void* p, size_t i, int f32) {
    return f32 ? ((const float*)p)[i]
               : __bfloat162float(((const __hip_bfloat16*)p)[i]);
}
__device__ __forceinline__ int ldI(const void* p, size_t i, int i64) {
    return i64 ? (int)((const long long*)p)[i] : ((const int*)p)[i];
}
__device__ __forceinline__ void stF(void* p, size_t i, float v, int f32) {
    if (f32) ((float*)p)[i] = v;
    else     ((__hip_bfloat16*)p)[i] = __float2bfloat16(v);
}

// ---------------- dtype sniffer ----------------------------------------------------
__global__ void GCNEncoder_77214922048129_kernel(const void* x, const void* ei,
                                                 int* flags) {
    __shared__ int cnt_weird, cnt_zero;
    if (threadIdx.x == 0) { cnt_weird = 0; cnt_zero = 0; }
    __syncthreads();
    const unsigned short* u = (const unsigned short*)x;
    int w = 0;
    for (int i = threadIdx.x; i < 2048; i += 256) {
        int e = (u[i] >> 7) & 0xFF;
        if (e == 0xFF || e >= 159 || (e > 0 && e <= 95)) w++;
    }
    atomicAdd(&cnt_weird, w);
    const int* ii = (const int*)ei;
    int z = 0;
    for (int i = threadIdx.x; i < 128; i += 256) {
        if (ii[2 * i + 1] == 0) z++;
    }
    atomicAdd(&cnt_zero, z);
    __syncthreads();
    if (threadIdx.x == 0) {
        flags[0] = (cnt_weird > 64) ? 1 : 0;  // fp32 floats
        flags[1] = (cnt_zero > 64) ? 1 : 0;   // int64 indices
    }
}

// ---------------- degree over col (self-loop added analytically) -------------------
__global__ void k_deg(const void* __restrict__ ei, int* __restrict__ deg,
                      const int* __restrict__ flags) {
    const int i64 = flags[1];
    int e = blockIdx.x * blockDim.x + threadIdx.x;
    if (e < N_EDGES) atomicAdd(&deg[ldI(ei, (size_t)N_EDGES + e, i64)], 1);
}

__global__ void k_dinv(const int* __restrict__ deg, float* __restrict__ dinv) {
    int i = blockIdx.x * blockDim.x + threadIdx.x;
    if (i < N_NODES) dinv[i] = rsqrtf((float)deg[i] + 1.0f);  // +1 = self-loop
}

// ---------------- CSR build: 3-stage parallel exclusive scan of deg ----------------
#define NB_SCAN ((N_NODES + 255) / 256)  // 391

__global__ __launch_bounds__(256) void k_bsum(const int* __restrict__ deg,
                                              int* __restrict__ bsum) {
    __shared__ int sh[256];
    int idx = blockIdx.x * 256 + threadIdx.x;
    sh[threadIdx.x] = (idx < N_NODES) ? deg[idx] : 0;
    __syncthreads();
#pragma unroll
    for (int off = 128; off > 0; off >>= 1) {
        if (threadIdx.x < off) sh[threadIdx.x] += sh[threadIdx.x + off];
        __syncthreads();
    }
    if (threadIdx.x == 0) bsum[blockIdx.x] = sh[0];
}

__global__ __launch_bounds__(512) void k_bscan(const int* __restrict__ bsum,
                                               int* __restrict__ bbase) {
    __shared__ int sh[512];
    const int t = threadIdx.x;
    sh[t] = (t < NB_SCAN) ? bsum[t] : 0;
    __syncthreads();
    for (int off = 1; off < 512; off <<= 1) {
        int v = (t >= off) ? sh[t - off] : 0;
        __syncthreads();
        sh[t] += v;
        __syncthreads();
    }
    if (t < NB_SCAN) bbase[t] = (t == 0) ? 0 : sh[t - 1];
}

__global__ __launch_bounds__(256) void k_rowptr(const int* __restrict__ deg,
                                                const int* __restrict__ bbase,
                                                int* __restrict__ rowptr,
                                                int* __restrict__ cursor) {
    __shared__ int sh[256];
    const int t = threadIdx.x;
    const int idx = blockIdx.x * 256 + t;
    const int d = (idx < N_NODES) ? deg[idx] : 0;
    sh[t] = d;
    __syncthreads();
    for (int off = 1; off < 256; off <<= 1) {
        int v = (t >= off) ? sh[t - off] : 0;
        __syncthreads();
        sh[t] += v;
        __syncthreads();
    }
    if (idx < N_NODES) {
        int r = bbase[blockIdx.x] + sh[t] - d;  // exclusive
        rowptr[idx] = r;
        cursor[idx] = r;
    }
    if (idx == 0) rowptr[N_NODES] = N_EDGES;
}

// ---------------- CSR scatter: src[pos(c)] = r -------------------------------------
__global__ __launch_bounds__(256) void k_csr(const void* __restrict__ ei,
                                             int* __restrict__ cursor,
                                             int* __restrict__ src,
                                             const int* __restrict__ flags) {
    const int i64 = flags[1];
    int e = blockIdx.x * blockDim.x + threadIdx.x;
    if (e < N_EDGES) {
        int r = ldI(ei, e, i64);
        int c = ldI(ei, (size_t)N_EDGES + e, i64);
        int pos = atomicAdd(&cursor[c], 1);
        src[pos] = r;
    }
}

// ---------------- GEMM1: h1s[n] = (x[n] @ W1) * dinv[n]  (fp32 out) ----------------
#define NPB1 64
__global__ __launch_bounds__(128) void k_gemm1(const void* __restrict__ x,
                                               const void* __restrict__ W1,
                                               const float* __restrict__ dinv,
                                               float* __restrict__ h1s,
                                               const int* __restrict__ flags) {
    const int F32 = flags[0];
    __shared__ float w1s[F_IN * F_MID];
    __shared__ float xs[F_IN];
    for (int i = threadIdx.x; i < F_IN * F_MID; i += 128) w1s[i] = ldF(W1, i, F32);
    const int f = threadIdx.x;
    const int n0 = blockIdx.x * NPB1;
    const int n1 = min(n0 + NPB1, N_NODES);
    for (int n = n0; n < n1; ++n) {
        __syncthreads();  // also covers w1s on first iteration
        if (threadIdx.x < F_IN) xs[threadIdx.x] = ldF(x, (size_t)n * F_IN + threadIdx.x, F32);
        __syncthreads();
        float acc = 0.f;
#pragma unroll
        for (int k = 0; k < F_IN; ++k) acc += xs[k] * w1s[k * F_MID + f];
        h1s[(size_t)n * F_MID + f] = acc * dinv[n];
    }
}

// ------ fused layer1: CSR gather-sum + self + dinv + b1 + LN + ReLU + GEMM2 --------
// one wave per node (grid-stride); 8 waves/block; scalar CSR loads + 4-deep MLP
#define G1W 8
__global__ __launch_bounds__(64 * G1W) void k_gather1(
    const int* __restrict__ rowptr, const int* __restrict__ src,
    const float* __restrict__ h1s, const float* __restrict__ dinv,
    const void* __restrict__ b1, const void* __restrict__ lnw,
    const void* __restrict__ lnb, const void* __restrict__ W2,
    float* __restrict__ a2s, const int* __restrict__ flags) {
    const int F32 = flags[0];
    __shared__ float w2s[F_MID * F_OUT];
    __shared__ float b1s[F_MID], lnws[F_MID], lnbs[F_MID];
    __shared__ float us[G1W][F_MID];
    for (int i = threadIdx.x; i < F_MID * F_OUT; i += 64 * G1W) w2s[i] = ldF(W2, i, F32);
    if (threadIdx.x < F_MID) {
        b1s[threadIdx.x] = ldF(b1, threadIdx.x, F32);
        lnws[threadIdx.x] = ldF(lnw, threadIdx.x, F32);
        lnbs[threadIdx.x] = ldF(lnb, threadIdx.x, F32);
    }
    __syncthreads();
    const int wid = threadIdx.x >> 6;
    const int lane = threadIdx.x & 63;
    const float2* __restrict__ h1v = (const float2*)h1s;  // row = 64 float2
    for (int n0 = blockIdx.x * G1W + wid; n0 < N_NODES; n0 += gridDim.x * G1W) {
        const int n = __builtin_amdgcn_readfirstlane(n0);  // force SGPR → scalar CSR loads
        const int beg = rowptr[n], end = rowptr[n + 1];
        float ax0 = 0.f, ay0 = 0.f, ax1 = 0.f, ay1 = 0.f;
        int jj = beg;
        for (; jj + 4 <= end; jj += 4) {
            const int r0 = src[jj], r1 = src[jj + 1], r2 = src[jj + 2], r3 = src[jj + 3];
            const float2 v0 = h1v[(size_t)r0 * 64 + lane];
            const float2 v1 = h1v[(size_t)r1 * 64 + lane];
            const float2 v2 = h1v[(size_t)r2 * 64 + lane];
            const float2 v3 = h1v[(size_t)r3 * 64 + lane];
            ax0 += v0.x + v1.x; ay0 += v0.y + v1.y;
            ax1 += v2.x + v3.x; ay1 += v2.y + v3.y;
        }
        for (; jj < end; ++jj) {
            const float2 v = h1v[(size_t)src[jj] * 64 + lane];
            ax0 += v.x; ay0 += v.y;
        }
        const float2 sv = h1v[(size_t)n * 64 + lane];
        const float dv = dinv[n];
        const float2 b1v = ((const float2*)b1s)[lane];
        float t0 = (ax0 + ax1 + sv.x) * dv + b1v.x;
        float t1 = (ay0 + ay1 + sv.y) * dv + b1v.y;
        float s = t0 + t1;
#pragma unroll
        for (int off = 32; off > 0; off >>= 1) s += __shfl_down(s, off, 64);
        const float mu = __shfl(s, 0, 64) * (1.f / 128.f);
        float d0 = t0 - mu, d1 = t1 - mu;
        float v = d0 * d0 + d1 * d1;
#pragma unroll
        for (int off = 32; off > 0; off >>= 1) v += __shfl_down(v, off, 64);
        const float rstd = rsqrtf(__shfl(v, 0, 64) * (1.f / 128.f) + 1e-5f);
        const float2 lwv = ((const float2*)lnws)[lane];
        const float2 lbv = ((const float2*)lnbs)[lane];
        float2 uv;
        uv.x = fmaxf(d0 * rstd * lwv.x + lbv.x, 0.f);
        uv.y = fmaxf(d1 * rstd * lwv.y + lbv.y, 0.f);
        ((float2*)&us[wid][0])[lane] = uv;  // within-wave RAW (lockstep, lgkmcnt wait)
        float acc = 0.f;
#pragma unroll
        for (int k = 0; k < F_MID; ++k) acc += us[wid][k] * w2s[k * F_OUT + lane];
        a2s[(size_t)n * F_OUT + lane] = acc * dv;
    }
}

// ------ fused layer2: CSR gather-sum + self + dinv + b2 → out (+fp32 keep) ---------
__global__ __launch_bounds__(256) void k_gather2(
    const int* __restrict__ rowptr, const int* __restrict__ src,
    const float* __restrict__ a2s, const float* __restrict__ dinv,
    const void* __restrict__ b2, void* __restrict__ out,
    float* __restrict__ h2f, const int* __restrict__ flags) {
    const int F32 = flags[0];
    __shared__ float b2s[F_OUT];
    if (threadIdx.x < F_OUT) b2s[threadIdx.x] = ldF(b2, threadIdx.x, F32);
    __syncthreads();
    const int wid = threadIdx.x >> 6;
    const int lane = threadIdx.x & 63;
    for (int n0 = blockIdx.x * 4 + wid; n0 < N_NODES; n0 += gridDim.x * 4) {
        const int n = __builtin_amdgcn_readfirstlane(n0);
        const int beg = rowptr[n], end = rowptr[n + 1];
        float a0 = 0.f, a1 = 0.f;
        int jj = beg;
        for (; jj + 8 <= end; jj += 8) {
            const float v0 = a2s[(size_t)src[jj + 0] * F_OUT + lane];
            const float v1 = a2s[(size_t)src[jj + 1] * F_OUT + lane];
            const float v2 = a2s[(size_t)src[jj + 2] * F_OUT + lane];
            const float v3 = a2s[(size_t)src[jj + 3] * F_OUT + lane];
            const float v4 = a2s[(size_t)src[jj + 4] * F_OUT + lane];
            const float v5 = a2s[(size_t)src[jj + 5] * F_OUT + lane];
            const float v6 = a2s[(size_t)src[jj + 6] * F_OUT + lane];
            const float v7 = a2s[(size_t)src[jj + 7] * F_OUT + lane];
            a0 += (v0 + v1) + (v2 + v3);
            a1 += (v4 + v5) + (v6 + v7);
        }
        for (; jj < end; ++jj) a0 += a2s[(size_t)src[jj] * F_OUT + lane];
        const size_t idx = (size_t)n * F_OUT + lane;
        float v = (a0 + a1 + a2s[idx]) * dinv[n] + b2s[lane];
        h2f[idx] = v;
        stF(out, idx, v, F32);
    }
}

// ---------------- per-graph counts via binary search on sorted batch ---------------
__global__ void k_counts(const void* __restrict__ batch, int* __restrict__ counts,
                         const int* __restrict__ flags) {
    const int i64 = flags[1];
    int g = threadIdx.x;
    if (g < N_GRAPHS) {
        int lo = 0, hi = N_NODES;
        while (lo < hi) { int m = (lo + hi) >> 1; if (ldI(batch, m, i64) < g) lo = m + 1; else hi = m; }
        int lb = lo;
        lo = 0; hi = N_NODES;
        while (lo < hi) { int m = (lo + hi) >> 1; if (ldI(batch, m, i64) <= g) lo = m + 1; else hi = m; }
        counts[g] = lo - lb;
    }
}

// ---------------- pooling: segmented per-wave reduction (batch sorted) -------------
__global__ __launch_bounds__(256) void k_pool(const float* __restrict__ h2,
                                              const void* __restrict__ batch,
                                              float* __restrict__ gsum,
                                              const int* __restrict__ flags) {
    const int i64 = flags[1];
    const int wid = (blockIdx.x * blockDim.x + threadIdx.x) >> 6;
    const int lane = threadIdx.x & 63;
    const int nwaves = (gridDim.x * blockDim.x) >> 6;
    const int per = (N_NODES + nwaves - 1) / nwaves;
    const int start = wid * per;
    const int end = min(start + per, N_NODES);
    if (start >= end) return;
    float acc = 0.f;
    int gcur = ldI(batch, start, i64);
    for (int n = start; n < end; ++n) {
        int g = ldI(batch, n, i64);
        if (g != gcur) {
            atomicAdd(&gsum[gcur * 64 + lane], acc);
            acc = 0.f;
            gcur = g;
        }
        acc += h2[(size_t)n * 64 + lane];
    }
    atomicAdd(&gsum[gcur * 64 + lane], acc);
}

__global__ void k_gout(const float* __restrict__ gsum, const int* __restrict__ counts,
                       void* __restrict__ out, const int* __restrict__ flags) {
    const int F32 = flags[0];
    int idx = blockIdx.x * blockDim.x + threadIdx.x;
    if (idx < N_GRAPHS * 64) {
        int g = idx >> 6;
        float c = (float)max(counts[g], 1);
        stF(out, (size_t)N_NODES * F_OUT + idx, gsum[idx] / c, F32);
    }
}

extern "C" void kernel_launch(void* const* d_in, const int* in_sizes, int n_in,
                              void* d_out, int out_size, void* d_ws, size_t ws_size,
                              hipStream_t stream) {
    const void* x   = d_in[0];
    const void* ei  = d_in[1];
    const void* bat = d_in[2];
    const void* W1  = d_in[3];
    const void* b1  = d_in[4];
    const void* lnw = d_in[5];
    const void* lnb = d_in[6];
    const void* W2  = d_in[7];
    const void* b2  = d_in[8];

    char* ws = (char*)d_ws;
    size_t o = 0;
    auto alloc = [&](size_t bytes) { size_t r = o; o += (bytes + 255) & ~(size_t)255; return r; };
    int*   flags  = (int*)  (ws + alloc(2 * 4));
    float* dinv   = (float*)(ws + alloc((size_t)N_NODES * 4));
    int*   deg    = (int*)  (ws + alloc((size_t)N_NODES * 4));
    int*   rowptr = (int*)  (ws + alloc((size_t)(N_NODES + 1) * 4));
    int*   cursor = (int*)  (ws + alloc((size_t)N_NODES * 4));
    int*   bsum   = (int*)  (ws + alloc((size_t)NB_SCAN * 4));
    int*   bbase  = (int*)  (ws + alloc((size_t)NB_SCAN * 4));
    int*   srcidx = (int*)  (ws + alloc((size_t)N_EDGES * 4));
    float* h1s    = (float*)(ws + alloc((size_t)N_NODES * F_MID * 4));
    float* a2s    = (float*)(ws + alloc((size_t)N_NODES * F_OUT * 4));
    float* h2f    = (float*)(ws + alloc((size_t)N_NODES * F_OUT * 4));
    float* gsum   = (float*)(ws + alloc((size_t)N_GRAPHS * 64 * 4));
    int*   counts = (int*)  (ws + alloc((size_t)N_GRAPHS * 4));

    hipMemsetAsync(deg, 0, (size_t)N_NODES * 4, stream);
    hipMemsetAsync(gsum, 0, (size_t)N_GRAPHS * 64 * 4, stream);

    GCNEncoder_77214922048129_kernel<<<1, 256, 0, stream>>>(x, ei, flags);
    k_deg<<<(N_EDGES + 255) / 256, 256, 0, stream>>>(ei, deg, flags);
    k_dinv<<<(N_NODES + 255) / 256, 256, 0, stream>>>(deg, dinv);
    k_bsum<<<NB_SCAN, 256, 0, stream>>>(deg, bsum);
    k_bscan<<<1, 512, 0, stream>>>(bsum, bbase);
    k_rowptr<<<NB_SCAN, 256, 0, stream>>>(deg, bbase, rowptr, cursor);
    k_csr<<<(N_EDGES + 255) / 256, 256, 0, stream>>>(ei, cursor, srcidx, flags);
    k_gemm1<<<(N_NODES + NPB1 - 1) / NPB1, 128, 0, stream>>>(x, W1, dinv, h1s, flags);
    k_gather1<<<1024, 64 * G1W, 0, stream>>>(rowptr, srcidx, h1s, dinv, b1, lnw, lnb, W2,
                                             a2s, flags);
    k_gather2<<<4096, 256, 0, stream>>>(rowptr, srcidx, a2s, dinv, b2, d_out, h2f, flags);
    k_counts<<<1, 64, 0, stream>>>(bat, counts, flags);
    k_pool<<<512, 256, 0, stream>>>(h2f, bat, gsum, flags);
    k_gout<<<(N_GRAPHS * 64 + 255) / 256, 256, 0, stream>>>(gsum, counts, d_out, flags);
}

// Round 6
// 603.748 us; speedup vs baseline: 2.6388x; 1.2718x over previous
//
#include <hip/hip_runtime.h>
#include <hip/hip_bf16.h>
#include <hip/hip_fp16.h>
#include <cstdint>

#define N_NODES 100000
#define N_EDGES 1600000
#define N_GRAPHS 64
#define F_IN 64
#define F_MID 128
#define F_OUT 64

typedef unsigned int uint32;

// ---- dtype-agnostic accessors (flags[0]=1 → floats are fp32; flags[1]=1 → ints are int64)
__device__ __forceinline__ float ldF(const void* p, size_t i, int f32) {
    return f32 ? ((const float*)p)[i]
               : __bfloat162float(((const __hip_bfloat16*)p)[i]);
}
__device__ __forceinline__ int ldI(const void* p, size_t i, int i64) {
    return i64 ? (int)((const long long*)p)[i] : ((const int*)p)[i];
}
__device__ __forceinline__ void stF(void* p, size_t i, float v, int f32) {
    if (f32) ((float*)p)[i] = v;
    else     ((__hip_bfloat16*)p)[i] = __float2bfloat16(v);
}

// ---- fp16x2 pack/unpack ----
union H2U { uint32 u; __half2 h; };
__device__ __forceinline__ float2 up16(uint32 u) {
    H2U c; c.u = u;
    return __half22float2(c.h);
}
__device__ __forceinline__ uint32 pk16(float a, float b) {
    H2U c; c.h = __floats2half2_rn(a, b);
    return c.u;
}
__device__ __forceinline__ unsigned short bfbits(float f) {
    __hip_bfloat16 b = __float2bfloat16(f);
    return *(unsigned short*)&b;
}

// ---------------- dtype sniffer ----------------------------------------------------
__global__ void GCNEncoder_77214922048129_kernel(const void* x, const void* ei,
                                                 int* flags) {
    __shared__ int cnt_weird, cnt_zero;
    if (threadIdx.x == 0) { cnt_weird = 0; cnt_zero = 0; }
    __syncthreads();
    const unsigned short* u = (const unsigned short*)x;
    int w = 0;
    for (int i = threadIdx.x; i < 2048; i += 256) {
        int e = (u[i] >> 7) & 0xFF;
        if (e == 0xFF || e >= 159 || (e > 0 && e <= 95)) w++;
    }
    atomicAdd(&cnt_weird, w);
    const int* ii = (const int*)ei;
    int z = 0;
    for (int i = threadIdx.x; i < 128; i += 256) {
        if (ii[2 * i + 1] == 0) z++;
    }
    atomicAdd(&cnt_zero, z);
    __syncthreads();
    if (threadIdx.x == 0) {
        flags[0] = (cnt_weird > 64) ? 1 : 0;  // fp32 floats
        flags[1] = (cnt_zero > 64) ? 1 : 0;   // int64 indices
    }
}

// ---------------- degree over col (self-loop added analytically) -------------------
__global__ void k_deg(const void* __restrict__ ei, int* __restrict__ deg,
                      const int* __restrict__ flags) {
    const int i64 = flags[1];
    int e = blockIdx.x * blockDim.x + threadIdx.x;
    if (e < N_EDGES) atomicAdd(&deg[ldI(ei, (size_t)N_EDGES + e, i64)], 1);
}

__global__ void k_dinv(const int* __restrict__ deg, float* __restrict__ dinv) {
    int i = blockIdx.x * blockDim.x + threadIdx.x;
    if (i < N_NODES) dinv[i] = rsqrtf((float)deg[i] + 1.0f);  // +1 = self-loop
}

// ---------------- CSR build: 3-stage parallel exclusive scan of deg ----------------
#define NB_SCAN ((N_NODES + 255) / 256)  // 391

__global__ __launch_bounds__(256) void k_bsum(const int* __restrict__ deg,
                                              int* __restrict__ bsum) {
    __shared__ int sh[256];
    int idx = blockIdx.x * 256 + threadIdx.x;
    sh[threadIdx.x] = (idx < N_NODES) ? deg[idx] : 0;
    __syncthreads();
#pragma unroll
    for (int off = 128; off > 0; off >>= 1) {
        if (threadIdx.x < off) sh[threadIdx.x] += sh[threadIdx.x + off];
        __syncthreads();
    }
    if (threadIdx.x == 0) bsum[blockIdx.x] = sh[0];
}

__global__ __launch_bounds__(512) void k_bscan(const int* __restrict__ bsum,
                                               int* __restrict__ bbase) {
    __shared__ int sh[512];
    const int t = threadIdx.x;
    sh[t] = (t < NB_SCAN) ? bsum[t] : 0;
    __syncthreads();
    for (int off = 1; off < 512; off <<= 1) {
        int v = (t >= off) ? sh[t - off] : 0;
        __syncthreads();
        sh[t] += v;
        __syncthreads();
    }
    if (t < NB_SCAN) bbase[t] = (t == 0) ? 0 : sh[t - 1];
}

__global__ __launch_bounds__(256) void k_rowptr(const int* __restrict__ deg,
                                                const int* __restrict__ bbase,
                                                int* __restrict__ rowptr,
                                                int* __restrict__ cursor) {
    __shared__ int sh[256];
    const int t = threadIdx.x;
    const int idx = blockIdx.x * 256 + t;
    const int d = (idx < N_NODES) ? deg[idx] : 0;
    sh[t] = d;
    __syncthreads();
    for (int off = 1; off < 256; off <<= 1) {
        int v = (t >= off) ? sh[t - off] : 0;
        __syncthreads();
        sh[t] += v;
        __syncthreads();
    }
    if (idx < N_NODES) {
        int r = bbase[blockIdx.x] + sh[t] - d;  // exclusive
        rowptr[idx] = r;
        cursor[idx] = r;
    }
    if (idx == 0) rowptr[N_NODES] = N_EDGES;
}

// ---------------- CSR scatter: src[pos(c)] = r -------------------------------------
__global__ __launch_bounds__(256) void k_csr(const void* __restrict__ ei,
                                             int* __restrict__ cursor,
                                             int* __restrict__ src,
                                             const int* __restrict__ flags) {
    const int i64 = flags[1];
    int e = blockIdx.x * blockDim.x + threadIdx.x;
    if (e < N_EDGES) {
        int r = ldI(ei, e, i64);
        int c = ldI(ei, (size_t)N_EDGES + e, i64);
        int pos = atomicAdd(&cursor[c], 1);
        src[pos] = r;
    }
}

// ---------------- xs16[n] = fp16( x[n] * dinv[n] ), packed pairs -------------------
__global__ __launch_bounds__(256) void k_scale(const void* __restrict__ x,
                                               const float* __restrict__ dinv,
                                               uint32* __restrict__ xs16,
                                               const int* __restrict__ flags) {
    const int F32 = flags[0];
    int idx = blockIdx.x * blockDim.x + threadIdx.x;  // feature-pair index
    if (idx < N_NODES * 32) {
        int n = idx >> 5;
        float dv = dinv[n];
        float a = ldF(x, (size_t)idx * 2, F32) * dv;
        float b = ldF(x, (size_t)idx * 2 + 1, F32) * dv;
        xs16[idx] = pk16(a, b);
    }
}

// ------ fused layer1: x-space gather (64-dim fp16) + GEMM1 + LN + ReLU + GEMM2 -----
// one wave per node (grid-stride); 8 waves/block; fp16-pair weights in LDS
#define G1W 8
__global__ __launch_bounds__(64 * G1W) void k_gather1(
    const int* __restrict__ rowptr, const int* __restrict__ src,
    const uint32* __restrict__ xsu, const float* __restrict__ dinv,
    const void* __restrict__ b1, const void* __restrict__ lnw,
    const void* __restrict__ lnb, const void* __restrict__ W1,
    const void* __restrict__ W2, uint32* __restrict__ a2u,
    const int* __restrict__ flags) {
    const int F32 = flags[0];
    __shared__ uint32 w1p[32 * F_MID];  // pair(k=2k2,2k2+1) of W1[k][f] ; 16 KB
    __shared__ uint32 w2p[64 * F_OUT];  // pair of W2[k][f] ; 16 KB
    __shared__ float b1s[F_MID], lnws[F_MID], lnbs[F_MID];
    __shared__ float us[G1W][F_MID];
    __shared__ float aggsh[G1W][F_IN];
    for (int i = threadIdx.x; i < 32 * F_MID; i += 64 * G1W) {
        int k2 = i >> 7, f = i & 127;
        w1p[i] = pk16(ldF(W1, (size_t)(2 * k2) * F_MID + f, F32),
                      ldF(W1, (size_t)(2 * k2 + 1) * F_MID + f, F32));
    }
    for (int i = threadIdx.x; i < 64 * F_OUT; i += 64 * G1W) {
        int k2 = i >> 6, f = i & 63;
        w2p[i] = pk16(ldF(W2, (size_t)(2 * k2) * F_OUT + f, F32),
                      ldF(W2, (size_t)(2 * k2 + 1) * F_OUT + f, F32));
    }
    if (threadIdx.x < F_MID) {
        b1s[threadIdx.x] = ldF(b1, threadIdx.x, F32);
        lnws[threadIdx.x] = ldF(lnw, threadIdx.x, F32);
        lnbs[threadIdx.x] = ldF(lnb, threadIdx.x, F32);
    }
    __syncthreads();
    const int wid = threadIdx.x >> 6;
    const int lane = threadIdx.x & 63;
    const int h = lane >> 5;    // which neighbor of the pair
    const int fp = lane & 31;   // feature-pair index
    for (int n0 = blockIdx.x * G1W + wid; n0 < N_NODES; n0 += gridDim.x * G1W) {
        const int n = __builtin_amdgcn_readfirstlane(n0);
        const int beg = rowptr[n], end = rowptr[n + 1];
        float2 a0 = {0.f, 0.f}, a1 = {0.f, 0.f};
        int jj = beg;
        for (; jj + 8 <= end; jj += 8) {
            const int p0 = src[jj], p1 = src[jj + 1], p2 = src[jj + 2], p3 = src[jj + 3];
            const int p4 = src[jj + 4], p5 = src[jj + 5], p6 = src[jj + 6], p7 = src[jj + 7];
            const int iA = h ? p1 : p0, iB = h ? p3 : p2, iC = h ? p5 : p4, iD = h ? p7 : p6;
            const float2 vA = up16(xsu[(size_t)iA * 32 + fp]);
            const float2 vB = up16(xsu[(size_t)iB * 32 + fp]);
            const float2 vC = up16(xsu[(size_t)iC * 32 + fp]);
            const float2 vD = up16(xsu[(size_t)iD * 32 + fp]);
            a0.x += vA.x + vC.x; a0.y += vA.y + vC.y;
            a1.x += vB.x + vD.x; a1.y += vB.y + vD.y;
        }
        for (; jj < end; jj += 2) {
            const int i0 = src[jj];
            const int i1 = (jj + 1 < end) ? src[jj + 1] : -1;
            const int ix = h ? i1 : i0;
            if (ix >= 0) {
                const float2 v = up16(xsu[(size_t)ix * 32 + fp]);
                a0.x += v.x; a0.y += v.y;
            }
        }
        float sx = a0.x + a1.x, sy = a0.y + a1.y;
        sx += __shfl_xor(sx, 32, 64);
        sy += __shfl_xor(sy, 32, 64);
        const float2 sv = up16(xsu[(size_t)n * 32 + fp]);  // self term (already * dinv)
        sx += sv.x; sy += sv.y;
        if (h == 0) ((float2*)aggsh[wid])[fp] = make_float2(sx, sy);
        // GEMM1: t[f] = (agg @ W1)[f] * dv + b1[f],  f = lane & lane+64
        const float dv = dinv[n];
        float g0 = 0.f, g1 = 0.f;
        const float2* aggv = (const float2*)aggsh[wid];
#pragma unroll
        for (int k2 = 0; k2 < 32; ++k2) {
            const float2 a = aggv[k2];
            const float2 wA = up16(w1p[k2 * F_MID + lane]);
            const float2 wB = up16(w1p[k2 * F_MID + lane + 64]);
            g0 += a.x * wA.x + a.y * wA.y;
            g1 += a.x * wB.x + a.y * wB.y;
        }
        float t0 = g0 * dv + b1s[lane];
        float t1 = g1 * dv + b1s[lane + 64];
        // LayerNorm over 128
        float s = t0 + t1;
#pragma unroll
        for (int off = 32; off > 0; off >>= 1) s += __shfl_down(s, off, 64);
        const float mu = __shfl(s, 0, 64) * (1.f / 128.f);
        float d0 = t0 - mu, d1 = t1 - mu;
        float v = d0 * d0 + d1 * d1;
#pragma unroll
        for (int off = 32; off > 0; off >>= 1) v += __shfl_down(v, off, 64);
        const float rstd = rsqrtf(__shfl(v, 0, 64) * (1.f / 128.f) + 1e-5f);
        const float u0 = fmaxf(d0 * rstd * lnws[lane] + lnbs[lane], 0.f);
        const float u1 = fmaxf(d1 * rstd * lnws[lane + 64] + lnbs[lane + 64], 0.f);
        us[wid][lane] = u0;
        us[wid][lane + 64] = u1;  // within-wave RAW (lockstep, lgkmcnt wait)
        // GEMM2: a2[lane] = (u @ W2)[lane] * dv
        float acc = 0.f;
        const float2* uv2 = (const float2*)us[wid];
#pragma unroll
        for (int k2 = 0; k2 < 64; ++k2) {
            const float2 u2 = uv2[k2];
            const float2 w = up16(w2p[k2 * F_OUT + lane]);
            acc += u2.x * w.x + u2.y * w.y;
        }
        const float a2 = acc * dv;
        const float partner = __shfl_down(a2, 1, 64);
        if ((lane & 1) == 0) a2u[(size_t)n * 32 + (lane >> 1)] = pk16(a2, partner);
    }
}

// ------ fused layer2: fp16 gather (64-dim) + self + dinv + b2 → out (+fp32 keep) ---
__global__ __launch_bounds__(256) void k_gather2(
    const int* __restrict__ rowptr, const int* __restrict__ src,
    const uint32* __restrict__ a2u, const float* __restrict__ dinv,
    const void* __restrict__ b2, void* __restrict__ out,
    float* __restrict__ h2f, const int* __restrict__ flags) {
    const int F32 = flags[0];
    __shared__ float b2s[F_OUT];
    if (threadIdx.x < F_OUT) b2s[threadIdx.x] = ldF(b2, threadIdx.x, F32);
    __syncthreads();
    const int wid = threadIdx.x >> 6;
    const int lane = threadIdx.x & 63;
    const int h = lane >> 5;
    const int fp = lane & 31;
    for (int n0 = blockIdx.x * 4 + wid; n0 < N_NODES; n0 += gridDim.x * 4) {
        const int n = __builtin_amdgcn_readfirstlane(n0);
        const int beg = rowptr[n], end = rowptr[n + 1];
        float2 a0 = {0.f, 0.f}, a1 = {0.f, 0.f};
        int jj = beg;
        for (; jj + 8 <= end; jj += 8) {
            const int p0 = src[jj], p1 = src[jj + 1], p2 = src[jj + 2], p3 = src[jj + 3];
            const int p4 = src[jj + 4], p5 = src[jj + 5], p6 = src[jj + 6], p7 = src[jj + 7];
            const int iA = h ? p1 : p0, iB = h ? p3 : p2, iC = h ? p5 : p4, iD = h ? p7 : p6;
            const float2 vA = up16(a2u[(size_t)iA * 32 + fp]);
            const float2 vB = up16(a2u[(size_t)iB * 32 + fp]);
            const float2 vC = up16(a2u[(size_t)iC * 32 + fp]);
            const float2 vD = up16(a2u[(size_t)iD * 32 + fp]);
            a0.x += vA.x + vC.x; a0.y += vA.y + vC.y;
            a1.x += vB.x + vD.x; a1.y += vB.y + vD.y;
        }
        for (; jj < end; jj += 2) {
            const int i0 = src[jj];
            const int i1 = (jj + 1 < end) ? src[jj + 1] : -1;
            const int ix = h ? i1 : i0;
            if (ix >= 0) {
                const float2 v = up16(a2u[(size_t)ix * 32 + fp]);
                a0.x += v.x; a0.y += v.y;
            }
        }
        float sx = a0.x + a1.x, sy = a0.y + a1.y;
        sx += __shfl_xor(sx, 32, 64);
        sy += __shfl_xor(sy, 32, 64);
        const float2 sv = up16(a2u[(size_t)n * 32 + fp]);  // self term
        const float dv = dinv[n];
        const float2 b2v = ((const float2*)b2s)[fp];
        float2 r;
        r.x = (sx + sv.x) * dv + b2v.x;
        r.y = (sy + sv.y) * dv + b2v.y;
        if (h == 0) {
            ((float2*)h2f)[(size_t)n * 32 + fp] = r;  // fp32 keep for pooling
            if (F32) {
                ((float2*)out)[(size_t)n * 32 + fp] = r;
            } else {
                uint32 ub = ((uint32)bfbits(r.y) << 16) | (uint32)bfbits(r.x);
                ((uint32*)out)[(size_t)n * 32 + fp] = ub;
            }
        }
    }
}

// ---------------- per-graph counts via binary search on sorted batch ---------------
__global__ void k_counts(const void* __restrict__ batch, int* __restrict__ counts,
                         const int* __restrict__ flags) {
    const int i64 = flags[1];
    int g = threadIdx.x;
    if (g < N_GRAPHS) {
        int lo = 0, hi = N_NODES;
        while (lo < hi) { int m = (lo + hi) >> 1; if (ldI(batch, m, i64) < g) lo = m + 1; else hi = m; }
        int lb = lo;
        lo = 0; hi = N_NODES;
        while (lo < hi) { int m = (lo + hi) >> 1; if (ldI(batch, m, i64) <= g) lo = m + 1; else hi = m; }
        counts[g] = lo - lb;
    }
}

// ---------------- pooling: segmented per-wave reduction (batch sorted) -------------
__global__ __launch_bounds__(256) void k_pool(const float* __restrict__ h2,
                                              const void* __restrict__ batch,
                                              float* __restrict__ gsum,
                                              const int* __restrict__ flags) {
    const int i64 = flags[1];
    const int wid = (blockIdx.x * blockDim.x + threadIdx.x) >> 6;
    const int lane = threadIdx.x & 63;
    const int nwaves = (gridDim.x * blockDim.x) >> 6;
    const int per = (N_NODES + nwaves - 1) / nwaves;
    const int start = wid * per;
    const int end = min(start + per, N_NODES);
    if (start >= end) return;
    float acc = 0.f;
    int gcur = ldI(batch, start, i64);
    for (int n = start; n < end; ++n) {
        int g = ldI(batch, n, i64);
        if (g != gcur) {
            atomicAdd(&gsum[gcur * 64 + lane], acc);
            acc = 0.f;
            gcur = g;
        }
        acc += h2[(size_t)n * 64 + lane];
    }
    atomicAdd(&gsum[gcur * 64 + lane], acc);
}

__global__ void k_gout(const float* __restrict__ gsum, const int* __restrict__ counts,
                       void* __restrict__ out, const int* __restrict__ flags) {
    const int F32 = flags[0];
    int idx = blockIdx.x * blockDim.x + threadIdx.x;
    if (idx < N_GRAPHS * 64) {
        int g = idx >> 6;
        float c = (float)max(counts[g], 1);
        stF(out, (size_t)N_NODES * F_OUT + idx, gsum[idx] / c, F32);
    }
}

extern "C" void kernel_launch(void* const* d_in, const int* in_sizes, int n_in,
                              void* d_out, int out_size, void* d_ws, size_t ws_size,
                              hipStream_t stream) {
    const void* x   = d_in[0];
    const void* ei  = d_in[1];
    const void* bat = d_in[2];
    const void* W1  = d_in[3];
    const void* b1  = d_in[4];
    const void* lnw = d_in[5];
    const void* lnb = d_in[6];
    const void* W2  = d_in[7];
    const void* b2  = d_in[8];

    char* ws = (char*)d_ws;
    size_t o = 0;
    auto alloc = [&](size_t bytes) { size_t r = o; o += (bytes + 255) & ~(size_t)255; return r; };
    int*    flags  = (int*)   (ws + alloc(2 * 4));
    float*  dinv   = (float*) (ws + alloc((size_t)N_NODES * 4));
    int*    deg    = (int*)   (ws + alloc((size_t)N_NODES * 4));
    int*    rowptr = (int*)   (ws + alloc((size_t)(N_NODES + 1) * 4));
    int*    cursor = (int*)   (ws + alloc((size_t)N_NODES * 4));
    int*    bsum   = (int*)   (ws + alloc((size_t)NB_SCAN * 4));
    int*    bbase  = (int*)   (ws + alloc((size_t)NB_SCAN * 4));
    int*    srcidx = (int*)   (ws + alloc((size_t)N_EDGES * 4));
    uint32* xs16   = (uint32*)(ws + alloc((size_t)N_NODES * 32 * 4));
    uint32* a2u    = (uint32*)(ws + alloc((size_t)N_NODES * 32 * 4));
    float*  h2f    = (float*) (ws + alloc((size_t)N_NODES * F_OUT * 4));
    float*  gsum   = (float*) (ws + alloc((size_t)N_GRAPHS * 64 * 4));
    int*    counts = (int*)   (ws + alloc((size_t)N_GRAPHS * 4));

    hipMemsetAsync(deg, 0, (size_t)N_NODES * 4, stream);
    hipMemsetAsync(gsum, 0, (size_t)N_GRAPHS * 64 * 4, stream);

    GCNEncoder_77214922048129_kernel<<<1, 256, 0, stream>>>(x, ei, flags);
    k_deg<<<(N_EDGES + 255) / 256, 256, 0, stream>>>(ei, deg, flags);
    k_dinv<<<(N_NODES + 255) / 256, 256, 0, stream>>>(deg, dinv);
    k_bsum<<<NB_SCAN, 256, 0, stream>>>(deg, bsum);
    k_bscan<<<1, 512, 0, stream>>>(bsum, bbase);
    k_rowptr<<<NB_SCAN, 256, 0, stream>>>(deg, bbase, rowptr, cursor);
    k_csr<<<(N_EDGES + 255) / 256, 256, 0, stream>>>(ei, cursor, srcidx, flags);
    k_scale<<<(N_NODES * 32 + 255) / 256, 256, 0, stream>>>(x, dinv, xs16, flags);
    k_gather1<<<1024, 64 * G1W, 0, stream>>>(rowptr, srcidx, xs16, dinv, b1, lnw, lnb,
                                             W1, W2, a2u, flags);
    k_gather2<<<4096, 256, 0, stream>>>(rowptr, srcidx, a2u, dinv, b2, d_out, h2f, flags);
    k_counts<<<1, 64, 0, stream>>>(bat, counts, flags);
    k_pool<<<512, 256, 0, stream>>>(h2f, bat, gsum, flags);
    k_gout<<<(N_GRAPHS * 64 + 255) / 256, 256, 0, stream>>>(gsum, counts, d_out, flags);
}